// Round 1
// baseline (15826.283 us; speedup 1.0000x reference)
//
#include <hip/hip_runtime.h>
#include <hip/hip_bf16.h>
#include <stdint.h>

typedef __bf16 bf16_t;
typedef __attribute__((ext_vector_type(8))) __bf16 bf16x8;
typedef __attribute__((ext_vector_type(4))) __bf16 bf16x4;
typedef __attribute__((ext_vector_type(4))) float f32x4;
typedef __attribute__((ext_vector_type(8))) unsigned short u16x8;

#define M_TOK 2304
#define DV    1024
#define DLAT  4096
#define VOCAB 32000

__device__ __forceinline__ float bf2f(unsigned short u) {
  union { unsigned int i; float f; } v; v.i = ((unsigned int)u) << 16; return v.f;
}
__device__ __forceinline__ bf16_t f2bf(float f) { return (bf16_t)f; }

constexpr int BM = 128, BN = 128, BK = 32;

// AMODE: 0 = A is bf16 (K-contiguous), 1 = A is f32 (K-contiguous, convert)
// BMODE: 0 = B is f32 NT ([N][K], K-contiguous), 1 = B is f32 NN ([K][N], N-contiguous, transpose-stage)
// EPI:   0 = f32 store + bias, 1 = bf16 store, 2 = f32 store
template<int AMODE, int BMODE, int EPI>
__global__ void __launch_bounds__(256, 2)
gemm_k(const void* __restrict__ Ap, const float* __restrict__ Bp,
       void* __restrict__ Cp, const float* __restrict__ bias,
       int K, int lda, int ldb, int ldc, int Mt)
{
  __shared__ __align__(16) bf16_t Al[2][BM * BK];
  __shared__ __align__(16) bf16_t Bl[2][BN * BK];

  const int bid = blockIdx.x;
  const int mt = bid % Mt, nt = bid / Mt;      // N-major: panel reuse via L2/L3
  const int m0 = mt * BM, n0 = nt * BN;
  const int t    = threadIdx.x;
  const int lane = t & 63, wv = t >> 6;
  const int wm = wv >> 1, wn = wv & 1;
  const int lr = lane & 15, kc = lane >> 4;

  f32x4 acc[4][4];
#pragma unroll
  for (int i = 0; i < 4; ++i)
#pragma unroll
    for (int j = 0; j < 4; ++j)
#pragma unroll
      for (int r = 0; r < 4; ++r) acc[i][j][r] = 0.0f;

  const int sm_r = t >> 1, sm_h = t & 1;   // NT staging: row, k-half
  const int tv = t & 7, te = t >> 3;       // NN transpose staging: v-group, e-group

  bf16x8 a_bf[2];
  f32x4  a_f32[4];
  f32x4  b_f32[4];

  const int NT = K / BK;

  auto LOADS = [&](int kt) {
    const int k0 = kt * BK;
    if (AMODE == 0) {
      const bf16_t* asrc = (const bf16_t*)Ap + (size_t)(m0 + sm_r) * lda + k0 + sm_h * 16;
      a_bf[0] = *(const bf16x8*)(asrc);
      a_bf[1] = *(const bf16x8*)(asrc + 8);
    } else {
      const float* asrc = (const float*)Ap + (size_t)(m0 + sm_r) * lda + k0 + sm_h * 16;
#pragma unroll
      for (int c = 0; c < 4; ++c) a_f32[c] = *(const f32x4*)(asrc + c * 4);
    }
    if (BMODE == 0) {
      const float* bsrc = Bp + (size_t)(n0 + sm_r) * ldb + k0 + sm_h * 16;
#pragma unroll
      for (int c = 0; c < 4; ++c) b_f32[c] = *(const f32x4*)(bsrc + c * 4);
    } else {
      const float* bsrc = Bp + (size_t)(k0 + tv * 4) * ldb + n0 + te * 4;
#pragma unroll
      for (int r = 0; r < 4; ++r) b_f32[r] = *(const f32x4*)(bsrc + (size_t)r * ldb);
    }
  };

  auto STORE_STAGE = [&](int nb) {
    // ---- A tile -> Al[nb], [128 rows][32 k] bf16 ----
    {
      bf16x8 w[2];
      if (AMODE == 0) {
        w[0] = a_bf[0]; w[1] = a_bf[1];
      } else {
#pragma unroll
        for (int j = 0; j < 2; ++j)
#pragma unroll
          for (int c = 0; c < 4; ++c) {
            w[j][c]     = f2bf(a_f32[2 * j][c]);
            w[j][c + 4] = f2bf(a_f32[2 * j + 1][c]);
          }
      }
      bf16_t* dst = &Al[nb][sm_r * BK + sm_h * 16];
      const int o0 = (sm_r >> 1) & 1;            // rotation: spread write banks
      *(bf16x8*)(dst + o0 * 8)       = w[o0];
      *(bf16x8*)(dst + (o0 ^ 1) * 8) = w[o0 ^ 1];
    }
    // ---- B tile -> Bl[nb], [128 n][32 k] bf16 ----
    if (BMODE == 0) {
      bf16x8 w[2];
#pragma unroll
      for (int j = 0; j < 2; ++j)
#pragma unroll
        for (int c = 0; c < 4; ++c) {
          w[j][c]     = f2bf(b_f32[2 * j][c]);
          w[j][c + 4] = f2bf(b_f32[2 * j + 1][c]);
        }
      bf16_t* dst = &Bl[nb][sm_r * BK + sm_h * 16];
      const int o0 = (sm_r >> 1) & 1;
      *(bf16x8*)(dst + o0 * 8)       = w[o0];
      *(bf16x8*)(dst + (o0 ^ 1) * 8) = w[o0 ^ 1];
    } else {
      // register 4x4 transpose; e-rotation spreads LDS write banks
#pragma unroll
      for (int i = 0; i < 4; ++i) {
        const int e = (i + te) & 3;
        bf16x4 w4;
        w4[0] = f2bf(b_f32[0][e]); w4[1] = f2bf(b_f32[1][e]);
        w4[2] = f2bf(b_f32[2][e]); w4[3] = f2bf(b_f32[3][e]);
        *(bf16x4*)(&Bl[nb][(te * 4 + e) * BK + tv * 4]) = w4;
      }
    }
  };

  auto COMPUTE = [&](int nb) {
    bf16x8 af[4], bfr[4];
#pragma unroll
    for (int f = 0; f < 4; ++f)
      af[f] = *(const bf16x8*)(&Al[nb][(wm * 64 + f * 16 + lr) * BK + kc * 8]);
#pragma unroll
    for (int f = 0; f < 4; ++f)
      bfr[f] = *(const bf16x8*)(&Bl[nb][(wn * 64 + f * 16 + lr) * BK + kc * 8]);
#pragma unroll
    for (int i = 0; i < 4; ++i)
#pragma unroll
      for (int j = 0; j < 4; ++j)
        acc[i][j] = __builtin_amdgcn_mfma_f32_16x16x32_bf16(af[i], bfr[j], acc[i][j], 0, 0, 0);
  };

  LOADS(0);
  STORE_STAGE(0);
  __syncthreads();
  int cur = 0;
  for (int kt = 0; kt < NT; ++kt) {
    const bool more = (kt + 1) < NT;
    if (more) LOADS(kt + 1);      // issue loads early (hide under MFMA)
    COMPUTE(cur);
    if (more) STORE_STAGE(cur ^ 1);
    __syncthreads();
    cur ^= 1;
  }

  // epilogue
#pragma unroll
  for (int j = 0; j < 4; ++j) {
    const int col = n0 + wn * 64 + j * 16 + lr;
    float bv = 0.0f;
    if (EPI == 0) bv = bias[col];
#pragma unroll
    for (int i = 0; i < 4; ++i) {
      const int row = m0 + wm * 64 + i * 16 + kc * 4;
      f32x4 a4 = acc[i][j];
      if (EPI == 0) {
        float* C = (float*)Cp;
#pragma unroll
        for (int r = 0; r < 4; ++r) C[(size_t)(row + r) * ldc + col] = a4[r] + bv;
      } else if (EPI == 1) {
        bf16_t* C = (bf16_t*)Cp;
#pragma unroll
        for (int r = 0; r < 4; ++r) C[(size_t)(row + r) * ldc + col] = f2bf(a4[r]);
      } else {
        float* C = (float*)Cp;
#pragma unroll
        for (int r = 0; r < 4; ++r) C[(size_t)(row + r) * ldc + col] = a4[r];
      }
    }
  }
}

// -------- LayerNorm over last dim (4096), f32 in -> bf16 out --------
__global__ void __launch_bounds__(256)
ln_k(const float* __restrict__ x, bf16_t* __restrict__ xn)
{
  __shared__ float sm[4];
  const int row = blockIdx.x, t = threadIdx.x;
  const float* xr = x + (size_t)row * DLAT;
  f32x4 v[4];
#pragma unroll
  for (int i = 0; i < 4; ++i) v[i] = *(const f32x4*)(xr + (t + i * 256) * 4);

  float s = 0.0f;
#pragma unroll
  for (int i = 0; i < 4; ++i)
#pragma unroll
    for (int j = 0; j < 4; ++j) s += v[i][j];
#pragma unroll
  for (int o = 32; o > 0; o >>= 1) s += __shfl_xor(s, o, 64);
  if ((t & 63) == 0) sm[t >> 6] = s;
  __syncthreads();
  const float mean = (sm[0] + sm[1] + sm[2] + sm[3]) * (1.0f / DLAT);
  __syncthreads();

  float q = 0.0f;
#pragma unroll
  for (int i = 0; i < 4; ++i)
#pragma unroll
    for (int j = 0; j < 4; ++j) { float d = v[i][j] - mean; q += d * d; }
#pragma unroll
  for (int o = 32; o > 0; o >>= 1) q += __shfl_xor(q, o, 64);
  if ((t & 63) == 0) sm[t >> 6] = q;
  __syncthreads();
  const float varr = (sm[0] + sm[1] + sm[2] + sm[3]) * (1.0f / DLAT);
  const float rs = rsqrtf(varr + 1e-5f);

  bf16_t* outr = xn + (size_t)row * DLAT;
#pragma unroll
  for (int i = 0; i < 4; ++i) {
    bf16x4 o;
#pragma unroll
    for (int j = 0; j < 4; ++j) o[j] = f2bf((v[i][j] - mean) * rs);
    *(bf16x4*)(outr + (t + i * 256) * 4) = o;
  }
}

// -------- row softmax over V=32000, bf16 in-place (3 passes, row stays in L2) --------
__global__ void __launch_bounds__(256)
softmax_k(bf16_t* __restrict__ L)
{
  __shared__ float sm[4];
  const int row = blockIdx.x, t = threadIdx.x;
  bf16_t* lrow = L + (size_t)row * VOCAB;
  const u16x8* lv = (const u16x8*)lrow;
  const int NF = VOCAB / 8;   // 4000

  float m = -3.0e38f;
  for (int f = t; f < NF; f += 256) {
    u16x8 u = lv[f];
#pragma unroll
    for (int j = 0; j < 8; ++j) m = fmaxf(m, bf2f(u[j]));
  }
#pragma unroll
  for (int o = 32; o > 0; o >>= 1) m = fmaxf(m, __shfl_xor(m, o, 64));
  if ((t & 63) == 0) sm[t >> 6] = m;
  __syncthreads();
  m = fmaxf(fmaxf(sm[0], sm[1]), fmaxf(sm[2], sm[3]));
  __syncthreads();

  float s = 0.0f;
  for (int f = t; f < NF; f += 256) {
    u16x8 u = lv[f];
#pragma unroll
    for (int j = 0; j < 8; ++j) s += __expf(bf2f(u[j]) - m);
  }
#pragma unroll
  for (int o = 32; o > 0; o >>= 1) s += __shfl_xor(s, o, 64);
  if ((t & 63) == 0) sm[t >> 6] = s;
  __syncthreads();
  const float inv = 1.0f / (sm[0] + sm[1] + sm[2] + sm[3]);

  for (int f = t; f < NF; f += 256) {
    u16x8 u = lv[f];
    bf16x8 o;
#pragma unroll
    for (int j = 0; j < 8; ++j) o[j] = f2bf(__expf(bf2f(u[j]) - m) * inv);
    *(bf16x8*)(&lrow[f * 8]) = o;
  }
}

extern "C" void kernel_launch(void* const* d_in, const int* in_sizes, int n_in,
                              void* d_out, int out_size, void* d_ws, size_t ws_size,
                              hipStream_t stream)
{
  (void)in_sizes; (void)n_in; (void)out_size; (void)ws_size;
  const float* vision = (const float*)d_in[0];   // [2304][1024]
  const float* W1w    = (const float*)d_in[1];   // [4096][1024]
  const float* W1b    = (const float*)d_in[2];   // [4096]
  const float* W2w    = (const float*)d_in[3];   // [32000][4096]
  const float* Emb    = (const float*)d_in[4];   // [32000][4096]
  float* out = (float*)d_out;                    // [2304][4096]

  char* ws = (char*)d_ws;
  bf16_t* xn     = (bf16_t*)ws;                             // 18,874,368 B
  bf16_t* logits = (bf16_t*)(ws + 18874368);                // 147,456,000 B
  float*  xbuf   = (float*)(ws + 18874368 + 147456000);     // 37,748,736 B

  // 1) x = vision @ W1^T + b   (M=2304, N=4096, K=1024)
  gemm_k<1, 0, 0><<<dim3((M_TOK / BM) * (DLAT / BN)), dim3(256), 0, stream>>>(
      vision, W1w, xbuf, W1b, DV, DV, DV, DLAT, M_TOK / BM);

  // 2) xn = LayerNorm(x) -> bf16
  ln_k<<<dim3(M_TOK), dim3(256), 0, stream>>>(xbuf, xn);

  // 3) logits = xn @ W2^T -> bf16   (M=2304, N=32000, K=4096)
  gemm_k<0, 0, 1><<<dim3((M_TOK / BM) * (VOCAB / BN)), dim3(256), 0, stream>>>(
      xn, W2w, logits, nullptr, DLAT, DLAT, DLAT, VOCAB, M_TOK / BM);

  // 4) P = softmax(logits) in place
  softmax_k<<<dim3(M_TOK), dim3(256), 0, stream>>>(logits);

  // 5) out = P @ Emb   (M=2304, N=4096, K=32000; B is NN layout -> transpose-stage)
  gemm_k<0, 1, 2><<<dim3((M_TOK / BM) * (DLAT / BN)), dim3(256), 0, stream>>>(
      logits, Emb, out, nullptr, VOCAB, VOCAB, DLAT, DLAT, M_TOK / BM);
}

// Round 2
// 3595.824 us; speedup vs baseline: 4.4013x; 4.4013x over previous
//
#include <hip/hip_runtime.h>
#include <hip/hip_bf16.h>
#include <stdint.h>

typedef __bf16 bf16_t;
typedef __attribute__((ext_vector_type(8))) __bf16 bf16x8;
typedef __attribute__((ext_vector_type(4))) __bf16 bf16x4;
typedef __attribute__((ext_vector_type(4))) float f32x4;
typedef __attribute__((ext_vector_type(8))) unsigned short u16x8;

#define M_TOK 2304
#define DV    1024
#define DLAT  4096
#define VOCAB 32000

__device__ __forceinline__ float bf2f(unsigned short u) {
  union { unsigned int i; float f; } v; v.i = ((unsigned int)u) << 16; return v.f;
}
__device__ __forceinline__ bf16_t f2bf(float f) { return (bf16_t)f; }

constexpr int BM = 128, BN = 128, BK = 32;
constexpr int BKP = BK + 8;   // padded LDS row stride (80 B): breaks the 8-way
                              // bank conflict of 64 B rows; keeps 16 B alignment

// AMODE: 0 = A is bf16 (K-contiguous), 1 = A is f32 (K-contiguous, convert)
// BMODE: 0 = B is f32 NT ([N][K], K-contiguous), 1 = B is f32 NN ([K][N], N-contiguous, transpose-stage)
// EPI:   0 = f32 store + bias, 1 = bf16 store, 2 = f32 store
template<int AMODE, int BMODE, int EPI>
__global__ void __launch_bounds__(256, 3)
gemm_k(const void* __restrict__ Ap, const float* __restrict__ Bp,
       void* __restrict__ Cp, const float* __restrict__ bias,
       int K, int lda, int ldb, int ldc, int Mt)
{
  __shared__ __align__(16) bf16_t Al[2][BM * BKP];
  __shared__ __align__(16) bf16_t Bl[2][BN * BKP];

  const int bid = blockIdx.x;
  const int mt = bid % Mt, nt = bid / Mt;      // N-major: B-panel reuse via L2/L3
  const int m0 = mt * BM, n0 = nt * BN;
  const int t    = threadIdx.x;
  const int lane = t & 63, wv = t >> 6;
  const int wm = wv >> 1, wn = wv & 1;
  const int lr = lane & 15, kc = lane >> 4;

  f32x4 acc[4][4];
#pragma unroll
  for (int i = 0; i < 4; ++i)
#pragma unroll
    for (int j = 0; j < 4; ++j)
#pragma unroll
      for (int r = 0; r < 4; ++r) acc[i][j][r] = 0.0f;

  const int sm_r = t >> 1, sm_h = t & 1;   // NT staging: row, k-half (16 elems each)
  const int tv = t & 7, te = t >> 3;       // NN transpose staging: k-group, n-group

  bf16x8 a_bf0, a_bf1;          // AMODE 0
  f32x4  a_f0, a_f1, a_f2, a_f3; // AMODE 1
  f32x4  b_f0, b_f1, b_f2, b_f3; // f32 B loads

  const int NT = K / BK;

  auto LOADS = [&](int kt) {
    const int k0 = kt * BK;
    if (AMODE == 0) {
      const bf16_t* asrc = (const bf16_t*)Ap + (size_t)(m0 + sm_r) * lda + k0 + sm_h * 16;
      a_bf0 = *(const bf16x8*)(asrc);
      a_bf1 = *(const bf16x8*)(asrc + 8);
    } else {
      const float* asrc = (const float*)Ap + (size_t)(m0 + sm_r) * lda + k0 + sm_h * 16;
      a_f0 = *(const f32x4*)(asrc);
      a_f1 = *(const f32x4*)(asrc + 4);
      a_f2 = *(const f32x4*)(asrc + 8);
      a_f3 = *(const f32x4*)(asrc + 12);
    }
    if (BMODE == 0) {
      const float* bsrc = Bp + (size_t)(n0 + sm_r) * ldb + k0 + sm_h * 16;
      b_f0 = *(const f32x4*)(bsrc);
      b_f1 = *(const f32x4*)(bsrc + 4);
      b_f2 = *(const f32x4*)(bsrc + 8);
      b_f3 = *(const f32x4*)(bsrc + 12);
    } else {
      const float* bsrc = Bp + (size_t)(k0 + tv * 4) * ldb + n0 + te * 4;
      b_f0 = *(const f32x4*)(bsrc);
      b_f1 = *(const f32x4*)(bsrc + (size_t)ldb);
      b_f2 = *(const f32x4*)(bsrc + (size_t)2 * ldb);
      b_f3 = *(const f32x4*)(bsrc + (size_t)3 * ldb);
    }
  };

  auto STORE_STAGE = [&](int nb) {
    // ---- A tile -> Al[nb], [128 rows][BKP] bf16, only first 32 k used ----
    {
      bf16x8 w0, w1;
      if (AMODE == 0) {
        w0 = a_bf0; w1 = a_bf1;
      } else {
#pragma unroll
        for (int c = 0; c < 4; ++c) {
          w0[c] = f2bf(a_f0[c]); w0[c + 4] = f2bf(a_f1[c]);
          w1[c] = f2bf(a_f2[c]); w1[c + 4] = f2bf(a_f3[c]);
        }
      }
      bf16_t* dst = &Al[nb][sm_r * BKP + sm_h * 16];
      *(bf16x8*)(dst)     = w0;
      *(bf16x8*)(dst + 8) = w1;
    }
    // ---- B tile -> Bl[nb], [128 n][BKP] bf16 ----
    if (BMODE == 0) {
      bf16x8 w0, w1;
#pragma unroll
      for (int c = 0; c < 4; ++c) {
        w0[c] = f2bf(b_f0[c]); w0[c + 4] = f2bf(b_f1[c]);
        w1[c] = f2bf(b_f2[c]); w1[c + 4] = f2bf(b_f3[c]);
      }
      bf16_t* dst = &Bl[nb][sm_r * BKP + sm_h * 16];
      *(bf16x8*)(dst)     = w0;
      *(bf16x8*)(dst + 8) = w1;
    } else {
      // register 4x4 transpose, all indices compile-time (no scratch!)
#pragma unroll
      for (int i = 0; i < 4; ++i) {
        bf16x4 w4;
        w4[0] = f2bf(b_f0[i]); w4[1] = f2bf(b_f1[i]);
        w4[2] = f2bf(b_f2[i]); w4[3] = f2bf(b_f3[i]);
        *(bf16x4*)(&Bl[nb][(te * 4 + i) * BKP + tv * 4]) = w4;
      }
    }
  };

  auto COMPUTE = [&](int nb) {
    bf16x8 af[4], bfr[4];
#pragma unroll
    for (int f = 0; f < 4; ++f)
      af[f] = *(const bf16x8*)(&Al[nb][(wm * 64 + f * 16 + lr) * BKP + kc * 8]);
#pragma unroll
    for (int f = 0; f < 4; ++f)
      bfr[f] = *(const bf16x8*)(&Bl[nb][(wn * 64 + f * 16 + lr) * BKP + kc * 8]);
#pragma unroll
    for (int i = 0; i < 4; ++i)
#pragma unroll
      for (int j = 0; j < 4; ++j)
        acc[i][j] = __builtin_amdgcn_mfma_f32_16x16x32_bf16(af[i], bfr[j], acc[i][j], 0, 0, 0);
  };

  LOADS(0);
  STORE_STAGE(0);
  __syncthreads();
  int cur = 0;
  for (int kt = 0; kt < NT; ++kt) {
    const bool more = (kt + 1) < NT;
    if (more) LOADS(kt + 1);      // issue loads early (hide under MFMA)
    COMPUTE(cur);
    if (more) STORE_STAGE(cur ^ 1);
    __syncthreads();
    cur ^= 1;
  }

  // epilogue
#pragma unroll
  for (int j = 0; j < 4; ++j) {
    const int col = n0 + wn * 64 + j * 16 + lr;
    float bv = 0.0f;
    if (EPI == 0) bv = bias[col];
#pragma unroll
    for (int i = 0; i < 4; ++i) {
      const int row = m0 + wm * 64 + i * 16 + kc * 4;
      f32x4 a4 = acc[i][j];
      if (EPI == 0) {
        float* C = (float*)Cp;
#pragma unroll
        for (int r = 0; r < 4; ++r) C[(size_t)(row + r) * ldc + col] = a4[r] + bv;
      } else if (EPI == 1) {
        bf16_t* C = (bf16_t*)Cp;
#pragma unroll
        for (int r = 0; r < 4; ++r) C[(size_t)(row + r) * ldc + col] = f2bf(a4[r]);
      } else {
        float* C = (float*)Cp;
#pragma unroll
        for (int r = 0; r < 4; ++r) C[(size_t)(row + r) * ldc + col] = a4[r];
      }
    }
  }
}

// -------- LayerNorm over last dim (4096), f32 in -> bf16 out --------
__global__ void __launch_bounds__(256)
ln_k(const float* __restrict__ x, bf16_t* __restrict__ xn)
{
  __shared__ float sm[4];
  const int row = blockIdx.x, t = threadIdx.x;
  const float* xr = x + (size_t)row * DLAT;
  f32x4 v[4];
#pragma unroll
  for (int i = 0; i < 4; ++i) v[i] = *(const f32x4*)(xr + (t + i * 256) * 4);

  float s = 0.0f;
#pragma unroll
  for (int i = 0; i < 4; ++i)
#pragma unroll
    for (int j = 0; j < 4; ++j) s += v[i][j];
#pragma unroll
  for (int o = 32; o > 0; o >>= 1) s += __shfl_xor(s, o, 64);
  if ((t & 63) == 0) sm[t >> 6] = s;
  __syncthreads();
  const float mean = (sm[0] + sm[1] + sm[2] + sm[3]) * (1.0f / DLAT);
  __syncthreads();

  float q = 0.0f;
#pragma unroll
  for (int i = 0; i < 4; ++i)
#pragma unroll
    for (int j = 0; j < 4; ++j) { float d = v[i][j] - mean; q += d * d; }
#pragma unroll
  for (int o = 32; o > 0; o >>= 1) q += __shfl_xor(q, o, 64);
  if ((t & 63) == 0) sm[t >> 6] = q;
  __syncthreads();
  const float varr = (sm[0] + sm[1] + sm[2] + sm[3]) * (1.0f / DLAT);
  const float rs = rsqrtf(varr + 1e-5f);

  bf16_t* outr = xn + (size_t)row * DLAT;
#pragma unroll
  for (int i = 0; i < 4; ++i) {
    bf16x4 o;
#pragma unroll
    for (int j = 0; j < 4; ++j) o[j] = f2bf((v[i][j] - mean) * rs);
    *(bf16x4*)(outr + (t + i * 256) * 4) = o;
  }
}

// -------- row softmax over V=32000, bf16 in-place (3 passes, row stays in L2) --------
__global__ void __launch_bounds__(256)
softmax_k(bf16_t* __restrict__ L)
{
  __shared__ float sm[4];
  const int row = blockIdx.x, t = threadIdx.x;
  bf16_t* lrow = L + (size_t)row * VOCAB;
  const u16x8* lv = (const u16x8*)lrow;
  const int NF = VOCAB / 8;   // 4000

  float m = -3.0e38f;
  for (int f = t; f < NF; f += 256) {
    u16x8 u = lv[f];
#pragma unroll
    for (int j = 0; j < 8; ++j) m = fmaxf(m, bf2f(u[j]));
  }
#pragma unroll
  for (int o = 32; o > 0; o >>= 1) m = fmaxf(m, __shfl_xor(m, o, 64));
  if ((t & 63) == 0) sm[t >> 6] = m;
  __syncthreads();
  m = fmaxf(fmaxf(sm[0], sm[1]), fmaxf(sm[2], sm[3]));
  __syncthreads();

  float s = 0.0f;
  for (int f = t; f < NF; f += 256) {
    u16x8 u = lv[f];
#pragma unroll
    for (int j = 0; j < 8; ++j) s += __expf(bf2f(u[j]) - m);
  }
#pragma unroll
  for (int o = 32; o > 0; o >>= 1) s += __shfl_xor(s, o, 64);
  if ((t & 63) == 0) sm[t >> 6] = s;
  __syncthreads();
  const float inv = 1.0f / (sm[0] + sm[1] + sm[2] + sm[3]);

  for (int f = t; f < NF; f += 256) {
    u16x8 u = lv[f];
    bf16x8 o;
#pragma unroll
    for (int j = 0; j < 8; ++j) o[j] = f2bf(__expf(bf2f(u[j]) - m) * inv);
    *(bf16x8*)(&lrow[f * 8]) = o;
  }
}

extern "C" void kernel_launch(void* const* d_in, const int* in_sizes, int n_in,
                              void* d_out, int out_size, void* d_ws, size_t ws_size,
                              hipStream_t stream)
{
  (void)in_sizes; (void)n_in; (void)out_size; (void)ws_size;
  const float* vision = (const float*)d_in[0];   // [2304][1024]
  const float* W1w    = (const float*)d_in[1];   // [4096][1024]
  const float* W1b    = (const float*)d_in[2];   // [4096]
  const float* W2w    = (const float*)d_in[3];   // [32000][4096]
  const float* Emb    = (const float*)d_in[4];   // [32000][4096]
  float* out = (float*)d_out;                    // [2304][4096]

  char* ws = (char*)d_ws;
  bf16_t* xn     = (bf16_t*)ws;                             // 18,874,368 B
  bf16_t* logits = (bf16_t*)(ws + 18874368);                // 147,456,000 B
  float*  xbuf   = (float*)(ws + 18874368 + 147456000);     // 37,748,736 B

  // 1) x = vision @ W1^T + b   (M=2304, N=4096, K=1024)
  gemm_k<1, 0, 0><<<dim3((M_TOK / BM) * (DLAT / BN)), dim3(256), 0, stream>>>(
      vision, W1w, xbuf, W1b, DV, DV, DV, DLAT, M_TOK / BM);

  // 2) xn = LayerNorm(x) -> bf16
  ln_k<<<dim3(M_TOK), dim3(256), 0, stream>>>(xbuf, xn);

  // 3) logits = xn @ W2^T -> bf16   (M=2304, N=32000, K=4096)
  gemm_k<0, 0, 1><<<dim3((M_TOK / BM) * (VOCAB / BN)), dim3(256), 0, stream>>>(
      xn, W2w, logits, nullptr, DLAT, DLAT, DLAT, VOCAB, M_TOK / BM);

  // 4) P = softmax(logits) in place
  softmax_k<<<dim3(M_TOK), dim3(256), 0, stream>>>(logits);

  // 5) out = P @ Emb   (M=2304, N=4096, K=32000; B is NN layout -> transpose-stage)
  gemm_k<0, 1, 2><<<dim3((M_TOK / BM) * (DLAT / BN)), dim3(256), 0, stream>>>(
      logits, Emb, out, nullptr, VOCAB, VOCAB, DLAT, DLAT, M_TOK / BM);
}

// Round 3
// 3441.866 us; speedup vs baseline: 4.5982x; 1.0447x over previous
//
#include <hip/hip_runtime.h>
#include <hip/hip_bf16.h>
#include <stdint.h>

typedef __bf16 bf16_t;
typedef __attribute__((ext_vector_type(8))) __bf16 bf16x8;
typedef __attribute__((ext_vector_type(4))) __bf16 bf16x4;
typedef __attribute__((ext_vector_type(4))) float f32x4;
typedef __attribute__((ext_vector_type(8))) unsigned short u16x8;

#define M_TOK 2304
#define DV    1024
#define DLAT  4096
#define VOCAB 32000

__device__ __forceinline__ float bf2f(unsigned short u) {
  union { unsigned int i; float f; } v; v.i = ((unsigned int)u) << 16; return v.f;
}
__device__ __forceinline__ bf16_t f2bf(float f) { return (bf16_t)f; }

constexpr int BM = 256, BN = 128, BK = 32;
constexpr int SA = 40;   // padded LDS row stride (80 B): frag reads 2-way (free)

// AMODE: 0 = A bf16 (K-contig), 1 = A f32 (K-contig, convert)
// BMODE: 0 = B f32 NT ([N][K]), 1 = B f32 NN ([K][N], transpose-stage)
// EPI:   0 = f32 store + bias, 1 = bf16 store, 2 = f32 store
template<int AMODE, int BMODE, int EPI>
__global__ void __launch_bounds__(256, 2)
gemm_k(const void* __restrict__ Ap, const float* __restrict__ Bp,
       void* __restrict__ Cp, const float* __restrict__ bias,
       int K, int lda, int ldb, int ldc, int Mt)
{
  __shared__ __align__(16) bf16_t Al[2][BM * SA];  // 40960 B
  __shared__ __align__(16) bf16_t Bl[2][BN * SA];  // 20480 B

  // bijective XCD-chunked swizzle (m204): each XCD gets a contiguous wg range
  const int nwg = gridDim.x;
  const int orig = blockIdx.x;
  const int q = nwg >> 3, r = nwg & 7;
  const int xcd = orig & 7, idx = orig >> 3;
  const int wg = (xcd < r ? xcd * (q + 1) : r * (q + 1) + (xcd - r) * q) + idx;
  const int mt = wg % Mt, nt = wg / Mt;   // consecutive wg: same nt -> share B panel
  const int m0 = mt * BM, n0 = nt * BN;

  const int t    = threadIdx.x;
  const int lane = t & 63, wv = t >> 6;
  const int wm = wv >> 1, wn = wv & 1;     // wave grid 2(M) x 2(N)
  const int lr = lane & 15, kc = lane >> 4;

  f32x4 acc[8][4];
#pragma unroll
  for (int i = 0; i < 8; ++i)
#pragma unroll
    for (int j = 0; j < 4; ++j)
#pragma unroll
      for (int x = 0; x < 4; ++x) acc[i][j][x] = 0.0f;

  // staging index maps (all compile-time-static register use)
  const int bn_r = t >> 1, bn_h = t & 1;   // B NT: n-row, k-half
  const int tv = t & 7, te = t >> 3;       // B NN: k-group(4), n-group(4)

  bf16x8 a_bf0, a_bf1, a_bf2, a_bf3;                       // AMODE 0 (one row/thread)
  f32x4  a_f0, a_f1, a_f2, a_f3, a_f4, a_f5, a_f6, a_f7;   // AMODE 1
  f32x4  b_f0, b_f1, b_f2, b_f3;                           // B loads

  const int NT = K / BK;

  auto LOADS = [&](int kt) {
    const int k0 = kt * BK;
    if (AMODE == 0) {
      const bf16_t* asrc = (const bf16_t*)Ap + (size_t)(m0 + t) * lda + k0;
      a_bf0 = *(const bf16x8*)(asrc);
      a_bf1 = *(const bf16x8*)(asrc + 8);
      a_bf2 = *(const bf16x8*)(asrc + 16);
      a_bf3 = *(const bf16x8*)(asrc + 24);
    } else {
      const float* asrc = (const float*)Ap + (size_t)(m0 + t) * lda + k0;
      a_f0 = *(const f32x4*)(asrc);      a_f1 = *(const f32x4*)(asrc + 4);
      a_f2 = *(const f32x4*)(asrc + 8);  a_f3 = *(const f32x4*)(asrc + 12);
      a_f4 = *(const f32x4*)(asrc + 16); a_f5 = *(const f32x4*)(asrc + 20);
      a_f6 = *(const f32x4*)(asrc + 24); a_f7 = *(const f32x4*)(asrc + 28);
    }
    if (BMODE == 0) {
      const float* bsrc = Bp + (size_t)(n0 + bn_r) * ldb + k0 + bn_h * 16;
      b_f0 = *(const f32x4*)(bsrc);     b_f1 = *(const f32x4*)(bsrc + 4);
      b_f2 = *(const f32x4*)(bsrc + 8); b_f3 = *(const f32x4*)(bsrc + 12);
    } else {
      const float* bsrc = Bp + (size_t)(k0 + tv * 4) * ldb + n0 + te * 4;
      b_f0 = *(const f32x4*)(bsrc);
      b_f1 = *(const f32x4*)(bsrc + (size_t)ldb);
      b_f2 = *(const f32x4*)(bsrc + (size_t)2 * ldb);
      b_f3 = *(const f32x4*)(bsrc + (size_t)3 * ldb);
    }
  };

  auto STORE_STAGE = [&](int nb) {
    {
      bf16x8 w0, w1, w2, w3;
      if (AMODE == 0) {
        w0 = a_bf0; w1 = a_bf1; w2 = a_bf2; w3 = a_bf3;
      } else {
#pragma unroll
        for (int c = 0; c < 4; ++c) {
          w0[c] = f2bf(a_f0[c]); w0[c + 4] = f2bf(a_f1[c]);
          w1[c] = f2bf(a_f2[c]); w1[c + 4] = f2bf(a_f3[c]);
          w2[c] = f2bf(a_f4[c]); w2[c + 4] = f2bf(a_f5[c]);
          w3[c] = f2bf(a_f6[c]); w3[c + 4] = f2bf(a_f7[c]);
        }
      }
      bf16_t* dst = &Al[nb][t * SA];
      *(bf16x8*)(dst)      = w0;
      *(bf16x8*)(dst + 8)  = w1;
      *(bf16x8*)(dst + 16) = w2;
      *(bf16x8*)(dst + 24) = w3;
    }
    if (BMODE == 0) {
      bf16x8 w0, w1;
#pragma unroll
      for (int c = 0; c < 4; ++c) {
        w0[c] = f2bf(b_f0[c]); w0[c + 4] = f2bf(b_f1[c]);
        w1[c] = f2bf(b_f2[c]); w1[c + 4] = f2bf(b_f3[c]);
      }
      bf16_t* dst = &Bl[nb][bn_r * SA + bn_h * 16];
      *(bf16x8*)(dst)     = w0;
      *(bf16x8*)(dst + 8) = w1;
    } else {
#pragma unroll
      for (int i = 0; i < 4; ++i) {
        bf16x4 w4;
        w4[0] = f2bf(b_f0[i]); w4[1] = f2bf(b_f1[i]);
        w4[2] = f2bf(b_f2[i]); w4[3] = f2bf(b_f3[i]);
        *(bf16x4*)(&Bl[nb][(te * 4 + i) * SA + tv * 4]) = w4;
      }
    }
  };

  auto COMPUTE = [&](int nb) {
    bf16x8 af[8], bfv[4];
#pragma unroll
    for (int f = 0; f < 8; ++f)
      af[f] = *(const bf16x8*)(&Al[nb][(wm * 128 + f * 16 + lr) * SA + kc * 8]);
#pragma unroll
    for (int f = 0; f < 4; ++f)
      bfv[f] = *(const bf16x8*)(&Bl[nb][(wn * 64 + f * 16 + lr) * SA + kc * 8]);
#pragma unroll
    for (int i = 0; i < 8; ++i)
#pragma unroll
      for (int j = 0; j < 4; ++j)
        acc[i][j] = __builtin_amdgcn_mfma_f32_16x16x32_bf16(af[i], bfv[j], acc[i][j], 0, 0, 0);
  };

  LOADS(0);
  STORE_STAGE(0);
  __syncthreads();
  int cur = 0;
  for (int kt = 0; kt < NT; ++kt) {
    const bool more = (kt + 1) < NT;
    if (more) LOADS(kt + 1);        // issue next-tile loads (fly under MFMA)
    COMPUTE(cur);                   // reads buf[cur] only
    if (more) STORE_STAGE(cur ^ 1); // waits loads, writes other buffer (no race:
                                    // cur^1 readers finished at prev barrier)
    __syncthreads();
    cur ^= 1;
  }

  // epilogue
#pragma unroll
  for (int j = 0; j < 4; ++j) {
    const int col = n0 + wn * 64 + j * 16 + lr;
    float bv = 0.0f;
    if (EPI == 0) bv = bias[col];
#pragma unroll
    for (int i = 0; i < 8; ++i) {
      const int row = m0 + wm * 128 + i * 16 + kc * 4;
      f32x4 a4 = acc[i][j];
      if (EPI == 0) {
        float* C = (float*)Cp;
#pragma unroll
        for (int x = 0; x < 4; ++x) C[(size_t)(row + x) * ldc + col] = a4[x] + bv;
      } else if (EPI == 1) {
        bf16_t* C = (bf16_t*)Cp;
#pragma unroll
        for (int x = 0; x < 4; ++x) C[(size_t)(row + x) * ldc + col] = f2bf(a4[x]);
      } else {
        float* C = (float*)Cp;
#pragma unroll
        for (int x = 0; x < 4; ++x) C[(size_t)(row + x) * ldc + col] = a4[x];
      }
    }
  }
}

// -------- LayerNorm over last dim (4096), f32 in -> bf16 out --------
__global__ void __launch_bounds__(256)
ln_k(const float* __restrict__ x, bf16_t* __restrict__ xn)
{
  __shared__ float sm[4];
  const int row = blockIdx.x, t = threadIdx.x;
  const float* xr = x + (size_t)row * DLAT;
  f32x4 v[4];
#pragma unroll
  for (int i = 0; i < 4; ++i) v[i] = *(const f32x4*)(xr + (t + i * 256) * 4);

  float s = 0.0f;
#pragma unroll
  for (int i = 0; i < 4; ++i)
#pragma unroll
    for (int j = 0; j < 4; ++j) s += v[i][j];
#pragma unroll
  for (int o = 32; o > 0; o >>= 1) s += __shfl_xor(s, o, 64);
  if ((t & 63) == 0) sm[t >> 6] = s;
  __syncthreads();
  const float mean = (sm[0] + sm[1] + sm[2] + sm[3]) * (1.0f / DLAT);
  __syncthreads();

  float qv = 0.0f;
#pragma unroll
  for (int i = 0; i < 4; ++i)
#pragma unroll
    for (int j = 0; j < 4; ++j) { float d = v[i][j] - mean; qv += d * d; }
#pragma unroll
  for (int o = 32; o > 0; o >>= 1) qv += __shfl_xor(qv, o, 64);
  if ((t & 63) == 0) sm[t >> 6] = qv;
  __syncthreads();
  const float varr = (sm[0] + sm[1] + sm[2] + sm[3]) * (1.0f / DLAT);
  const float rs = rsqrtf(varr + 1e-5f);

  bf16_t* outr = xn + (size_t)row * DLAT;
#pragma unroll
  for (int i = 0; i < 4; ++i) {
    bf16x4 o;
#pragma unroll
    for (int j = 0; j < 4; ++j) o[j] = f2bf((v[i][j] - mean) * rs);
    *(bf16x4*)(outr + (t + i * 256) * 4) = o;
  }
}

// -------- row softmax over V=32000, bf16 in-place, row staged in LDS --------
__global__ void __launch_bounds__(256)
softmax_k(bf16_t* __restrict__ L)
{
  __shared__ __align__(16) bf16_t rs_[VOCAB];   // 64000 B
  __shared__ float sm[4];
  const int row = blockIdx.x, t = threadIdx.x;
  bf16_t* lrow = L + (size_t)row * VOCAB;
  const int NF = VOCAB / 8;   // 4000

  // load row to LDS + running max
  float m = -3.0e38f;
  for (int f = t; f < NF; f += 256) {
    u16x8 u = *(const u16x8*)(&lrow[f * 8]);
    *(u16x8*)(&rs_[f * 8]) = u;
#pragma unroll
    for (int j = 0; j < 8; ++j) m = fmaxf(m, bf2f(u[j]));
  }
#pragma unroll
  for (int o = 32; o > 0; o >>= 1) m = fmaxf(m, __shfl_xor(m, o, 64));
  if ((t & 63) == 0) sm[t >> 6] = m;
  __syncthreads();
  m = fmaxf(fmaxf(sm[0], sm[1]), fmaxf(sm[2], sm[3]));
  __syncthreads();

  float s = 0.0f;
  for (int f = t; f < NF; f += 256) {
    u16x8 u = *(const u16x8*)(&rs_[f * 8]);
#pragma unroll
    for (int j = 0; j < 8; ++j) s += __expf(bf2f(u[j]) - m);
  }
#pragma unroll
  for (int o = 32; o > 0; o >>= 1) s += __shfl_xor(s, o, 64);
  if ((t & 63) == 0) sm[t >> 6] = s;
  __syncthreads();
  const float inv = 1.0f / (sm[0] + sm[1] + sm[2] + sm[3]);

  for (int f = t; f < NF; f += 256) {
    u16x8 u = *(const u16x8*)(&rs_[f * 8]);
    bf16x8 o;
#pragma unroll
    for (int j = 0; j < 8; ++j) o[j] = f2bf(__expf(bf2f(u[j]) - m) * inv);
    *(bf16x8*)(&lrow[f * 8]) = o;
  }
}

extern "C" void kernel_launch(void* const* d_in, const int* in_sizes, int n_in,
                              void* d_out, int out_size, void* d_ws, size_t ws_size,
                              hipStream_t stream)
{
  (void)in_sizes; (void)n_in; (void)out_size; (void)ws_size;
  const float* vision = (const float*)d_in[0];   // [2304][1024]
  const float* W1w    = (const float*)d_in[1];   // [4096][1024]
  const float* W1b    = (const float*)d_in[2];   // [4096]
  const float* W2w    = (const float*)d_in[3];   // [32000][4096]
  const float* Emb    = (const float*)d_in[4];   // [32000][4096]
  float* out = (float*)d_out;                    // [2304][4096]

  char* ws = (char*)d_ws;
  bf16_t* xn     = (bf16_t*)ws;                             // 18,874,368 B
  bf16_t* logits = (bf16_t*)(ws + 18874368);                // 147,456,000 B
  float*  xbuf   = (float*)(ws + 18874368 + 147456000);     // 37,748,736 B

  const int Mt = M_TOK / BM;  // 9

  // 1) x = vision @ W1^T + b   (M=2304, N=4096, K=1024) — grid 288, co-resident
  gemm_k<1, 0, 0><<<dim3(Mt * (DLAT / BN)), dim3(256), 0, stream>>>(
      vision, W1w, xbuf, W1b, DV, DV, DV, DLAT, Mt);

  // 2) xn = LayerNorm(x) -> bf16
  ln_k<<<dim3(M_TOK), dim3(256), 0, stream>>>(xbuf, xn);

  // 3) logits = xn @ W2^T -> bf16   (M=2304, N=32000, K=4096) — grid 2250
  gemm_k<0, 0, 1><<<dim3(Mt * (VOCAB / BN)), dim3(256), 0, stream>>>(
      xn, W2w, logits, nullptr, DLAT, DLAT, DLAT, VOCAB, Mt);

  // 4) P = softmax(logits) in place
  softmax_k<<<dim3(M_TOK), dim3(256), 0, stream>>>(logits);

  // 5) out = P @ Emb   (M=2304, N=4096, K=32000, NN) — grid 288, co-resident
  gemm_k<0, 1, 2><<<dim3(Mt * (DLAT / BN)), dim3(256), 0, stream>>>(
      logits, Emb, out, nullptr, VOCAB, VOCAB, DLAT, DLAT, Mt);
}

// Round 4
// 3144.263 us; speedup vs baseline: 5.0334x; 1.0946x over previous
//
#include <hip/hip_runtime.h>
#include <hip/hip_bf16.h>
#include <stdint.h>

typedef __bf16 bf16_t;
typedef __attribute__((ext_vector_type(8))) __bf16 bf16x8;
typedef __attribute__((ext_vector_type(4))) __bf16 bf16x4;
typedef __attribute__((ext_vector_type(4))) float f32x4;
typedef __attribute__((ext_vector_type(8))) unsigned short u16x8;

#define M_TOK 2304
#define DV    1024
#define DLAT  4096
#define VOCAB 32000

__device__ __forceinline__ float bf2f(unsigned short u) {
  union { unsigned int i; float f; } v; v.i = ((unsigned int)u) << 16; return v.f;
}
__device__ __forceinline__ bf16_t f2bf(float f) { return (bf16_t)f; }

constexpr int BM = 256, BN = 128, BK = 32;
constexpr int SA = 40;   // padded LDS row stride (80 B): frag reads 2-way (free)

// AMODE: 0 = A bf16 (K-contig), 1 = A f32 (K-contig, convert)
// BMODE: 0 = B f32 NT ([N][K]), 1 = B f32 NN ([K][N], transpose-stage)
// EPI:   0 = f32 store + bias, 1 = bf16 store, 2 = f32 store
template<int AMODE, int BMODE, int EPI>
__global__ void __launch_bounds__(256, 2)
gemm_k(const void* __restrict__ Ap, const float* __restrict__ Bp,
       void* __restrict__ Cp, const float* __restrict__ bias,
       int K, int lda, int ldb, int ldc, int Mt)
{
  __shared__ __align__(16) bf16_t Al[2][BM * SA];  // 40960 B
  __shared__ __align__(16) bf16_t Bl[2][BN * SA];  // 20480 B

  // bijective XCD-chunked swizzle (m204)
  const int nwg = gridDim.x;
  const int orig = blockIdx.x;
  const int q = nwg >> 3, r = nwg & 7;
  const int xcd = orig & 7, idx = orig >> 3;
  const int wg = (xcd < r ? xcd * (q + 1) : r * (q + 1) + (xcd - r) * q) + idx;
  const int mt = wg % Mt, nt = wg / Mt;   // consecutive wg: share B panel
  const int m0 = mt * BM, n0 = nt * BN;

  const int t    = threadIdx.x;
  const int lane = t & 63, wv = t >> 6;
  const int wm = wv >> 1, wn = wv & 1;     // wave grid 2(M) x 2(N)
  const int lr = lane & 15, kc = lane >> 4;

  f32x4 acc[8][4];
#pragma unroll
  for (int i = 0; i < 8; ++i)
#pragma unroll
    for (int j = 0; j < 4; ++j)
#pragma unroll
      for (int x = 0; x < 4; ++x) acc[i][j][x] = 0.0f;

  const int bn_r = t >> 1, bn_h = t & 1;   // B NT: n-row, k-half
  const int tv = t & 7, te = t >> 3;       // B NN: k-group(4), n-group(4)

  // ---- two named prefetch register sets (static use only; rule #20) ----
  bf16x8 s1_ab0, s1_ab1, s1_ab2, s1_ab3;
  bf16x8 s2_ab0, s2_ab1, s2_ab2, s2_ab3;
  f32x4  s1_af0, s1_af1, s1_af2, s1_af3, s1_af4, s1_af5, s1_af6, s1_af7;
  f32x4  s2_af0, s2_af1, s2_af2, s2_af3, s2_af4, s2_af5, s2_af6, s2_af7;
  f32x4  s1_b0, s1_b1, s1_b2, s1_b3;
  f32x4  s2_b0, s2_b1, s2_b2, s2_b3;

  const int NT = K / BK;

  auto LOADS1 = [&](int kt) {
    const int k0 = kt * BK;
    if (AMODE == 0) {
      const bf16_t* asrc = (const bf16_t*)Ap + (size_t)(m0 + t) * lda + k0;
      s1_ab0 = *(const bf16x8*)(asrc);      s1_ab1 = *(const bf16x8*)(asrc + 8);
      s1_ab2 = *(const bf16x8*)(asrc + 16); s1_ab3 = *(const bf16x8*)(asrc + 24);
    } else {
      const float* asrc = (const float*)Ap + (size_t)(m0 + t) * lda + k0;
      s1_af0 = *(const f32x4*)(asrc);      s1_af1 = *(const f32x4*)(asrc + 4);
      s1_af2 = *(const f32x4*)(asrc + 8);  s1_af3 = *(const f32x4*)(asrc + 12);
      s1_af4 = *(const f32x4*)(asrc + 16); s1_af5 = *(const f32x4*)(asrc + 20);
      s1_af6 = *(const f32x4*)(asrc + 24); s1_af7 = *(const f32x4*)(asrc + 28);
    }
    if (BMODE == 0) {
      const float* bsrc = Bp + (size_t)(n0 + bn_r) * ldb + k0 + bn_h * 16;
      s1_b0 = *(const f32x4*)(bsrc);     s1_b1 = *(const f32x4*)(bsrc + 4);
      s1_b2 = *(const f32x4*)(bsrc + 8); s1_b3 = *(const f32x4*)(bsrc + 12);
    } else {
      const float* bsrc = Bp + (size_t)(k0 + tv * 4) * ldb + n0 + te * 4;
      s1_b0 = *(const f32x4*)(bsrc);
      s1_b1 = *(const f32x4*)(bsrc + (size_t)ldb);
      s1_b2 = *(const f32x4*)(bsrc + (size_t)2 * ldb);
      s1_b3 = *(const f32x4*)(bsrc + (size_t)3 * ldb);
    }
  };
  auto LOADS2 = [&](int kt) {
    const int k0 = kt * BK;
    if (AMODE == 0) {
      const bf16_t* asrc = (const bf16_t*)Ap + (size_t)(m0 + t) * lda + k0;
      s2_ab0 = *(const bf16x8*)(asrc);      s2_ab1 = *(const bf16x8*)(asrc + 8);
      s2_ab2 = *(const bf16x8*)(asrc + 16); s2_ab3 = *(const bf16x8*)(asrc + 24);
    } else {
      const float* asrc = (const float*)Ap + (size_t)(m0 + t) * lda + k0;
      s2_af0 = *(const f32x4*)(asrc);      s2_af1 = *(const f32x4*)(asrc + 4);
      s2_af2 = *(const f32x4*)(asrc + 8);  s2_af3 = *(const f32x4*)(asrc + 12);
      s2_af4 = *(const f32x4*)(asrc + 16); s2_af5 = *(const f32x4*)(asrc + 20);
      s2_af6 = *(const f32x4*)(asrc + 24); s2_af7 = *(const f32x4*)(asrc + 28);
    }
    if (BMODE == 0) {
      const float* bsrc = Bp + (size_t)(n0 + bn_r) * ldb + k0 + bn_h * 16;
      s2_b0 = *(const f32x4*)(bsrc);     s2_b1 = *(const f32x4*)(bsrc + 4);
      s2_b2 = *(const f32x4*)(bsrc + 8); s2_b3 = *(const f32x4*)(bsrc + 12);
    } else {
      const float* bsrc = Bp + (size_t)(k0 + tv * 4) * ldb + n0 + te * 4;
      s2_b0 = *(const f32x4*)(bsrc);
      s2_b1 = *(const f32x4*)(bsrc + (size_t)ldb);
      s2_b2 = *(const f32x4*)(bsrc + (size_t)2 * ldb);
      s2_b3 = *(const f32x4*)(bsrc + (size_t)3 * ldb);
    }
  };

  auto STORE1 = [&](int nb) {
    {
      bf16x8 w0, w1, w2, w3;
      if (AMODE == 0) {
        w0 = s1_ab0; w1 = s1_ab1; w2 = s1_ab2; w3 = s1_ab3;
      } else {
#pragma unroll
        for (int c = 0; c < 4; ++c) {
          w0[c] = f2bf(s1_af0[c]); w0[c + 4] = f2bf(s1_af1[c]);
          w1[c] = f2bf(s1_af2[c]); w1[c + 4] = f2bf(s1_af3[c]);
          w2[c] = f2bf(s1_af4[c]); w2[c + 4] = f2bf(s1_af5[c]);
          w3[c] = f2bf(s1_af6[c]); w3[c + 4] = f2bf(s1_af7[c]);
        }
      }
      bf16_t* dst = &Al[nb][t * SA];
      *(bf16x8*)(dst) = w0; *(bf16x8*)(dst + 8) = w1;
      *(bf16x8*)(dst + 16) = w2; *(bf16x8*)(dst + 24) = w3;
    }
    if (BMODE == 0) {
      bf16x8 w0, w1;
#pragma unroll
      for (int c = 0; c < 4; ++c) {
        w0[c] = f2bf(s1_b0[c]); w0[c + 4] = f2bf(s1_b1[c]);
        w1[c] = f2bf(s1_b2[c]); w1[c + 4] = f2bf(s1_b3[c]);
      }
      bf16_t* dst = &Bl[nb][bn_r * SA + bn_h * 16];
      *(bf16x8*)(dst) = w0; *(bf16x8*)(dst + 8) = w1;
    } else {
#pragma unroll
      for (int i = 0; i < 4; ++i) {
        bf16x4 w4;
        w4[0] = f2bf(s1_b0[i]); w4[1] = f2bf(s1_b1[i]);
        w4[2] = f2bf(s1_b2[i]); w4[3] = f2bf(s1_b3[i]);
        *(bf16x4*)(&Bl[nb][(te * 4 + i) * SA + tv * 4]) = w4;
      }
    }
  };
  auto STORE2 = [&](int nb) {
    {
      bf16x8 w0, w1, w2, w3;
      if (AMODE == 0) {
        w0 = s2_ab0; w1 = s2_ab1; w2 = s2_ab2; w3 = s2_ab3;
      } else {
#pragma unroll
        for (int c = 0; c < 4; ++c) {
          w0[c] = f2bf(s2_af0[c]); w0[c + 4] = f2bf(s2_af1[c]);
          w1[c] = f2bf(s2_af2[c]); w1[c + 4] = f2bf(s2_af3[c]);
          w2[c] = f2bf(s2_af4[c]); w2[c + 4] = f2bf(s2_af5[c]);
          w3[c] = f2bf(s2_af6[c]); w3[c + 4] = f2bf(s2_af7[c]);
        }
      }
      bf16_t* dst = &Al[nb][t * SA];
      *(bf16x8*)(dst) = w0; *(bf16x8*)(dst + 8) = w1;
      *(bf16x8*)(dst + 16) = w2; *(bf16x8*)(dst + 24) = w3;
    }
    if (BMODE == 0) {
      bf16x8 w0, w1;
#pragma unroll
      for (int c = 0; c < 4; ++c) {
        w0[c] = f2bf(s2_b0[c]); w0[c + 4] = f2bf(s2_b1[c]);
        w1[c] = f2bf(s2_b2[c]); w1[c + 4] = f2bf(s2_b3[c]);
      }
      bf16_t* dst = &Bl[nb][bn_r * SA + bn_h * 16];
      *(bf16x8*)(dst) = w0; *(bf16x8*)(dst + 8) = w1;
    } else {
#pragma unroll
      for (int i = 0; i < 4; ++i) {
        bf16x4 w4;
        w4[0] = f2bf(s2_b0[i]); w4[1] = f2bf(s2_b1[i]);
        w4[2] = f2bf(s2_b2[i]); w4[3] = f2bf(s2_b3[i]);
        *(bf16x4*)(&Bl[nb][(te * 4 + i) * SA + tv * 4]) = w4;
      }
    }
  };

  auto COMPUTE = [&](int nb) {
    bf16x8 af[8], bfv[4];
#pragma unroll
    for (int f = 0; f < 8; ++f)
      af[f] = *(const bf16x8*)(&Al[nb][(wm * 128 + f * 16 + lr) * SA + kc * 8]);
#pragma unroll
    for (int f = 0; f < 4; ++f)
      bfv[f] = *(const bf16x8*)(&Bl[nb][(wn * 64 + f * 16 + lr) * SA + kc * 8]);
#pragma unroll
    for (int i = 0; i < 8; ++i)
#pragma unroll
      for (int j = 0; j < 4; ++j)
        acc[i][j] = __builtin_amdgcn_mfma_f32_16x16x32_bf16(af[i], bfv[j], acc[i][j], 0, 0, 0);
  };

  // ---- depth-2 pipeline: tile t computes while t+1 stages and t+2 loads ----
  LOADS1(0);
  STORE1(0);          // waits set1 only
  LOADS2(1);          // in flight across the barrier
  __syncthreads();

  int kt = 0;
  for (; kt + 2 < NT; kt += 2) {
    LOADS1(kt + 2);   // issue into freed set1 (flies under MFMA + stage)
    COMPUTE(0);
    STORE2(1);        // counted wait: only set2 loads must land
    __syncthreads();
    LOADS2(kt + 3);
    COMPUTE(1);
    STORE1(0);
    __syncthreads();
  }
  // tail: exactly 2 tiles left (NT even): buf0 = tile kt, set2 = tile kt+1
  COMPUTE(0);
  STORE2(1);
  __syncthreads();
  COMPUTE(1);

  // epilogue
#pragma unroll
  for (int j = 0; j < 4; ++j) {
    const int col = n0 + wn * 64 + j * 16 + lr;
    float bv = 0.0f;
    if (EPI == 0) bv = bias[col];
#pragma unroll
    for (int i = 0; i < 8; ++i) {
      const int row = m0 + wm * 128 + i * 16 + kc * 4;
      f32x4 a4 = acc[i][j];
      if (EPI == 0) {
        float* C = (float*)Cp;
#pragma unroll
        for (int x = 0; x < 4; ++x) C[(size_t)(row + x) * ldc + col] = a4[x] + bv;
      } else if (EPI == 1) {
        bf16_t* C = (bf16_t*)Cp;
#pragma unroll
        for (int x = 0; x < 4; ++x) C[(size_t)(row + x) * ldc + col] = f2bf(a4[x]);
      } else {
        float* C = (float*)Cp;
#pragma unroll
        for (int x = 0; x < 4; ++x) C[(size_t)(row + x) * ldc + col] = a4[x];
      }
    }
  }
}

// -------- LayerNorm over last dim (4096), f32 in -> bf16 out --------
__global__ void __launch_bounds__(256)
ln_k(const float* __restrict__ x, bf16_t* __restrict__ xn)
{
  __shared__ float sm[4];
  const int row = blockIdx.x, t = threadIdx.x;
  const float* xr = x + (size_t)row * DLAT;
  f32x4 v[4];
#pragma unroll
  for (int i = 0; i < 4; ++i) v[i] = *(const f32x4*)(xr + (t + i * 256) * 4);

  float s = 0.0f;
#pragma unroll
  for (int i = 0; i < 4; ++i)
#pragma unroll
    for (int j = 0; j < 4; ++j) s += v[i][j];
#pragma unroll
  for (int o = 32; o > 0; o >>= 1) s += __shfl_xor(s, o, 64);
  if ((t & 63) == 0) sm[t >> 6] = s;
  __syncthreads();
  const float mean = (sm[0] + sm[1] + sm[2] + sm[3]) * (1.0f / DLAT);
  __syncthreads();

  float qv = 0.0f;
#pragma unroll
  for (int i = 0; i < 4; ++i)
#pragma unroll
    for (int j = 0; j < 4; ++j) { float d = v[i][j] - mean; qv += d * d; }
#pragma unroll
  for (int o = 32; o > 0; o >>= 1) qv += __shfl_xor(qv, o, 64);
  if ((t & 63) == 0) sm[t >> 6] = qv;
  __syncthreads();
  const float varr = (sm[0] + sm[1] + sm[2] + sm[3]) * (1.0f / DLAT);
  const float rs = rsqrtf(varr + 1e-5f);

  bf16_t* outr = xn + (size_t)row * DLAT;
#pragma unroll
  for (int i = 0; i < 4; ++i) {
    bf16x4 o;
#pragma unroll
    for (int j = 0; j < 4; ++j) o[j] = f2bf((v[i][j] - mean) * rs);
    *(bf16x4*)(outr + (t + i * 256) * 4) = o;
  }
}

// -------- row softmax over V=32000, bf16 in-place, row staged in LDS --------
__global__ void __launch_bounds__(256)
softmax_k(bf16_t* __restrict__ L)
{
  __shared__ __align__(16) bf16_t rs_[VOCAB];   // 64000 B
  __shared__ float sm[4];
  const int row = blockIdx.x, t = threadIdx.x;
  bf16_t* lrow = L + (size_t)row * VOCAB;
  const int NF = VOCAB / 8;   // 4000

  float m = -3.0e38f;
  for (int f = t; f < NF; f += 256) {
    u16x8 u = *(const u16x8*)(&lrow[f * 8]);
    *(u16x8*)(&rs_[f * 8]) = u;
#pragma unroll
    for (int j = 0; j < 8; ++j) m = fmaxf(m, bf2f(u[j]));
  }
#pragma unroll
  for (int o = 32; o > 0; o >>= 1) m = fmaxf(m, __shfl_xor(m, o, 64));
  if ((t & 63) == 0) sm[t >> 6] = m;
  __syncthreads();
  m = fmaxf(fmaxf(sm[0], sm[1]), fmaxf(sm[2], sm[3]));
  __syncthreads();

  float s = 0.0f;
  for (int f = t; f < NF; f += 256) {
    u16x8 u = *(const u16x8*)(&rs_[f * 8]);
#pragma unroll
    for (int j = 0; j < 8; ++j) s += __expf(bf2f(u[j]) - m);
  }
#pragma unroll
  for (int o = 32; o > 0; o >>= 1) s += __shfl_xor(s, o, 64);
  if ((t & 63) == 0) sm[t >> 6] = s;
  __syncthreads();
  const float inv = 1.0f / (sm[0] + sm[1] + sm[2] + sm[3]);

  for (int f = t; f < NF; f += 256) {
    u16x8 u = *(const u16x8*)(&rs_[f * 8]);
    bf16x8 o;
#pragma unroll
    for (int j = 0; j < 8; ++j) o[j] = f2bf(__expf(bf2f(u[j]) - m) * inv);
    *(bf16x8*)(&lrow[f * 8]) = o;
  }
}

extern "C" void kernel_launch(void* const* d_in, const int* in_sizes, int n_in,
                              void* d_out, int out_size, void* d_ws, size_t ws_size,
                              hipStream_t stream)
{
  (void)in_sizes; (void)n_in; (void)out_size; (void)ws_size;
  const float* vision = (const float*)d_in[0];   // [2304][1024]
  const float* W1w    = (const float*)d_in[1];   // [4096][1024]
  const float* W1b    = (const float*)d_in[2];   // [4096]
  const float* W2w    = (const float*)d_in[3];   // [32000][4096]
  const float* Emb    = (const float*)d_in[4];   // [32000][4096]
  float* out = (float*)d_out;                    // [2304][4096]

  char* ws = (char*)d_ws;
  bf16_t* xn     = (bf16_t*)ws;                             // 18,874,368 B
  bf16_t* logits = (bf16_t*)(ws + 18874368);                // 147,456,000 B
  float*  xbuf   = (float*)(ws + 18874368 + 147456000);     // 37,748,736 B

  const int Mt = M_TOK / BM;  // 9

  // 1) x = vision @ W1^T + b   (M=2304, N=4096, K=1024)
  gemm_k<1, 0, 0><<<dim3(Mt * (DLAT / BN)), dim3(256), 0, stream>>>(
      vision, W1w, xbuf, W1b, DV, DV, DV, DLAT, Mt);

  // 2) xn = LayerNorm(x) -> bf16
  ln_k<<<dim3(M_TOK), dim3(256), 0, stream>>>(xbuf, xn);

  // 3) logits = xn @ W2^T -> bf16   (M=2304, N=32000, K=4096)
  gemm_k<0, 0, 1><<<dim3(Mt * (VOCAB / BN)), dim3(256), 0, stream>>>(
      xn, W2w, logits, nullptr, DLAT, DLAT, DLAT, VOCAB, Mt);

  // 4) P = softmax(logits) in place
  softmax_k<<<dim3(M_TOK), dim3(256), 0, stream>>>(logits);

  // 5) out = P @ Emb   (M=2304, N=4096, K=32000, NN)
  gemm_k<0, 1, 2><<<dim3(Mt * (DLAT / BN)), dim3(256), 0, stream>>>(
      logits, Emb, out, nullptr, VOCAB, VOCAB, DLAT, DLAT, Mt);
}

// Round 5
// 3052.622 us; speedup vs baseline: 5.1845x; 1.0300x over previous
//
#include <hip/hip_runtime.h>
#include <hip/hip_bf16.h>
#include <stdint.h>

typedef __bf16 bf16_t;
typedef __attribute__((ext_vector_type(8))) __bf16 bf16x8;
typedef __attribute__((ext_vector_type(4))) __bf16 bf16x4;
typedef __attribute__((ext_vector_type(4))) float f32x4;
typedef __attribute__((ext_vector_type(8))) unsigned short u16x8;

#define M_TOK 2304
#define DV    1024
#define DLAT  4096
#define VOCAB 32000

__device__ __forceinline__ float bf2f(unsigned short u) {
  union { unsigned int i; float f; } v; v.i = ((unsigned int)u) << 16; return v.f;
}
__device__ __forceinline__ bf16_t f2bf(float f) { return (bf16_t)f; }

// BM=96: GEMM1/GEMM3 grids = 24*32 = 768 = exactly 3 blocks/CU (perfect
// balance; 3 waves/SIMD TLP covers the per-tile barrier drain).
constexpr int BM = 96, BN = 128, BK = 32;
constexpr int SA = 40;   // padded LDS row stride (80 B): frag reads 2-way (free)

// AMODE: 0 = A bf16 (K-contig), 1 = A f32 (K-contig, convert)
// BMODE: 0 = B f32 NT ([N][K]), 1 = B f32 NN ([K][N], transpose-stage)
// EPI:   0 = f32 store + bias, 1 = bf16 store, 2 = f32 store
template<int AMODE, int BMODE, int EPI>
__global__ void __launch_bounds__(256, 3)
gemm_k(const void* __restrict__ Ap, const float* __restrict__ Bp,
       void* __restrict__ Cp, const float* __restrict__ bias,
       int K, int lda, int ldb, int ldc, int Mt)
{
  __shared__ __align__(16) bf16_t Al[2][BM * SA];  // 15360 B
  __shared__ __align__(16) bf16_t Bl[2][BN * SA];  // 20480 B

  // bijective XCD-chunked swizzle (m204)
  const int nwg = gridDim.x;
  const int orig = blockIdx.x;
  const int q = nwg >> 3, r = nwg & 7;
  const int xcd = orig & 7, idx = orig >> 3;
  const int wg = (xcd < r ? xcd * (q + 1) : r * (q + 1) + (xcd - r) * q) + idx;
  const int mt = wg % Mt, nt = wg / Mt;   // consecutive wg: share B panel
  const int m0 = mt * BM, n0 = nt * BN;

  const int t    = threadIdx.x;
  const int lane = t & 63, wv = t >> 6;
  const int wm = wv >> 1, wn = wv & 1;     // wave grid 2(M) x 2(N); per-wave 48x64
  const int lr = lane & 15, kc = lane >> 4;

  f32x4 acc[3][4];
#pragma unroll
  for (int i = 0; i < 3; ++i)
#pragma unroll
    for (int j = 0; j < 4; ++j)
#pragma unroll
      for (int x = 0; x < 4; ++x) acc[i][j][x] = 0.0f;

  const int ar = t >> 1, ah = t & 1;       // A staging: row (0..127, use <96), k-half
  const bool a_act = (t < 192);            // waves 0-2 stage A; wave 3 idle (uniform)
  const int bn_r = t >> 1, bn_h = t & 1;   // B NT: n-row, k-half
  const int tv = t & 7, te = t >> 3;       // B NN: k-group(4), n-group(4 cols)

  bf16x8 a_bf0, a_bf1;            // AMODE 0
  f32x4  a_f0, a_f1, a_f2, a_f3;  // AMODE 1
  f32x4  b_f0, b_f1, b_f2, b_f3;  // B loads

  const int NT = K / BK;

  auto LOADS = [&](int kt) {
    const int k0 = kt * BK;
    if (a_act) {
      if (AMODE == 0) {
        const bf16_t* asrc = (const bf16_t*)Ap + (size_t)(m0 + ar) * lda + k0 + ah * 16;
        a_bf0 = *(const bf16x8*)(asrc);
        a_bf1 = *(const bf16x8*)(asrc + 8);
      } else {
        const float* asrc = (const float*)Ap + (size_t)(m0 + ar) * lda + k0 + ah * 16;
        a_f0 = *(const f32x4*)(asrc);     a_f1 = *(const f32x4*)(asrc + 4);
        a_f2 = *(const f32x4*)(asrc + 8); a_f3 = *(const f32x4*)(asrc + 12);
      }
    }
    if (BMODE == 0) {
      const float* bsrc = Bp + (size_t)(n0 + bn_r) * ldb + k0 + bn_h * 16;
      b_f0 = *(const f32x4*)(bsrc);     b_f1 = *(const f32x4*)(bsrc + 4);
      b_f2 = *(const f32x4*)(bsrc + 8); b_f3 = *(const f32x4*)(bsrc + 12);
    } else {
      const float* bsrc = Bp + (size_t)(k0 + tv * 4) * ldb + n0 + te * 4;
      b_f0 = *(const f32x4*)(bsrc);
      b_f1 = *(const f32x4*)(bsrc + (size_t)ldb);
      b_f2 = *(const f32x4*)(bsrc + (size_t)2 * ldb);
      b_f3 = *(const f32x4*)(bsrc + (size_t)3 * ldb);
    }
  };

  auto STORE_STAGE = [&](int nb) {
    if (a_act) {
      bf16x8 w0, w1;
      if (AMODE == 0) {
        w0 = a_bf0; w1 = a_bf1;
      } else {
#pragma unroll
        for (int c = 0; c < 4; ++c) {
          w0[c] = f2bf(a_f0[c]); w0[c + 4] = f2bf(a_f1[c]);
          w1[c] = f2bf(a_f2[c]); w1[c + 4] = f2bf(a_f3[c]);
        }
      }
      bf16_t* dst = &Al[nb][ar * SA + ah * 16];
      *(bf16x8*)(dst)     = w0;
      *(bf16x8*)(dst + 8) = w1;
    }
    if (BMODE == 0) {
      bf16x8 w0, w1;
#pragma unroll
      for (int c = 0; c < 4; ++c) {
        w0[c] = f2bf(b_f0[c]); w0[c + 4] = f2bf(b_f1[c]);
        w1[c] = f2bf(b_f2[c]); w1[c + 4] = f2bf(b_f3[c]);
      }
      bf16_t* dst = &Bl[nb][bn_r * SA + bn_h * 16];
      *(bf16x8*)(dst)     = w0;
      *(bf16x8*)(dst + 8) = w1;
    } else {
#pragma unroll
      for (int i = 0; i < 4; ++i) {
        bf16x4 w4;
        w4[0] = f2bf(b_f0[i]); w4[1] = f2bf(b_f1[i]);
        w4[2] = f2bf(b_f2[i]); w4[3] = f2bf(b_f3[i]);
        *(bf16x4*)(&Bl[nb][(te * 4 + i) * SA + tv * 4]) = w4;
      }
    }
  };

  auto COMPUTE = [&](int nb) {
    bf16x8 af[3], bfv[4];
#pragma unroll
    for (int f = 0; f < 3; ++f)
      af[f] = *(const bf16x8*)(&Al[nb][(wm * 48 + f * 16 + lr) * SA + kc * 8]);
#pragma unroll
    for (int f = 0; f < 4; ++f)
      bfv[f] = *(const bf16x8*)(&Bl[nb][(wn * 64 + f * 16 + lr) * SA + kc * 8]);
#pragma unroll
    for (int i = 0; i < 3; ++i)
#pragma unroll
      for (int j = 0; j < 4; ++j)
        acc[i][j] = __builtin_amdgcn_mfma_f32_16x16x32_bf16(af[i], bfv[j], acc[i][j], 0, 0, 0);
  };

  LOADS(0);
  STORE_STAGE(0);
  __syncthreads();
  int cur = 0;
  for (int kt = 0; kt < NT; ++kt) {
    const bool more = (kt + 1) < NT;
    if (more) LOADS(kt + 1);        // issue next-tile loads under MFMA
    COMPUTE(cur);
    if (more) STORE_STAGE(cur ^ 1);
    __syncthreads();
    cur ^= 1;
  }

  // epilogue
#pragma unroll
  for (int j = 0; j < 4; ++j) {
    const int col = n0 + wn * 64 + j * 16 + lr;
    float bv = 0.0f;
    if (EPI == 0) bv = bias[col];
#pragma unroll
    for (int i = 0; i < 3; ++i) {
      const int row = m0 + wm * 48 + i * 16 + kc * 4;
      f32x4 a4 = acc[i][j];
      if (EPI == 0) {
        float* C = (float*)Cp;
#pragma unroll
        for (int x = 0; x < 4; ++x) C[(size_t)(row + x) * ldc + col] = a4[x] + bv;
      } else if (EPI == 1) {
        bf16_t* C = (bf16_t*)Cp;
#pragma unroll
        for (int x = 0; x < 4; ++x) C[(size_t)(row + x) * ldc + col] = f2bf(a4[x]);
      } else {
        float* C = (float*)Cp;
#pragma unroll
        for (int x = 0; x < 4; ++x) C[(size_t)(row + x) * ldc + col] = a4[x];
      }
    }
  }
}

// -------- LayerNorm over last dim (4096), f32 in -> bf16 out --------
__global__ void __launch_bounds__(256)
ln_k(const float* __restrict__ x, bf16_t* __restrict__ xn)
{
  __shared__ float sm[4];
  const int row = blockIdx.x, t = threadIdx.x;
  const float* xr = x + (size_t)row * DLAT;
  f32x4 v[4];
#pragma unroll
  for (int i = 0; i < 4; ++i) v[i] = *(const f32x4*)(xr + (t + i * 256) * 4);

  float s = 0.0f;
#pragma unroll
  for (int i = 0; i < 4; ++i)
#pragma unroll
    for (int j = 0; j < 4; ++j) s += v[i][j];
#pragma unroll
  for (int o = 32; o > 0; o >>= 1) s += __shfl_xor(s, o, 64);
  if ((t & 63) == 0) sm[t >> 6] = s;
  __syncthreads();
  const float mean = (sm[0] + sm[1] + sm[2] + sm[3]) * (1.0f / DLAT);
  __syncthreads();

  float qv = 0.0f;
#pragma unroll
  for (int i = 0; i < 4; ++i)
#pragma unroll
    for (int j = 0; j < 4; ++j) { float d = v[i][j] - mean; qv += d * d; }
#pragma unroll
  for (int o = 32; o > 0; o >>= 1) qv += __shfl_xor(qv, o, 64);
  if ((t & 63) == 0) sm[t >> 6] = qv;
  __syncthreads();
  const float varr = (sm[0] + sm[1] + sm[2] + sm[3]) * (1.0f / DLAT);
  const float rs = rsqrtf(varr + 1e-5f);

  bf16_t* outr = xn + (size_t)row * DLAT;
#pragma unroll
  for (int i = 0; i < 4; ++i) {
    bf16x4 o;
#pragma unroll
    for (int j = 0; j < 4; ++j) o[j] = f2bf((v[i][j] - mean) * rs);
    *(bf16x4*)(outr + (t + i * 256) * 4) = o;
  }
}

// -------- row softmax over V=32000, bf16 in-place, row staged in LDS --------
__global__ void __launch_bounds__(256)
softmax_k(bf16_t* __restrict__ L)
{
  __shared__ __align__(16) bf16_t rs_[VOCAB];   // 64000 B
  __shared__ float sm[4];
  const int row = blockIdx.x, t = threadIdx.x;
  bf16_t* lrow = L + (size_t)row * VOCAB;
  const int NF = VOCAB / 8;   // 4000

  float m = -3.0e38f;
  for (int f = t; f < NF; f += 256) {
    u16x8 u = *(const u16x8*)(&lrow[f * 8]);
    *(u16x8*)(&rs_[f * 8]) = u;
#pragma unroll
    for (int j = 0; j < 8; ++j) m = fmaxf(m, bf2f(u[j]));
  }
#pragma unroll
  for (int o = 32; o > 0; o >>= 1) m = fmaxf(m, __shfl_xor(m, o, 64));
  if ((t & 63) == 0) sm[t >> 6] = m;
  __syncthreads();
  m = fmaxf(fmaxf(sm[0], sm[1]), fmaxf(sm[2], sm[3]));
  __syncthreads();

  float s = 0.0f;
  for (int f = t; f < NF; f += 256) {
    u16x8 u = *(const u16x8*)(&rs_[f * 8]);
#pragma unroll
    for (int j = 0; j < 8; ++j) s += __expf(bf2f(u[j]) - m);
  }
#pragma unroll
  for (int o = 32; o > 0; o >>= 1) s += __shfl_xor(s, o, 64);
  if ((t & 63) == 0) sm[t >> 6] = s;
  __syncthreads();
  const float inv = 1.0f / (sm[0] + sm[1] + sm[2] + sm[3]);

  for (int f = t; f < NF; f += 256) {
    u16x8 u = *(const u16x8*)(&rs_[f * 8]);
    bf16x8 o;
#pragma unroll
    for (int j = 0; j < 8; ++j) o[j] = f2bf(__expf(bf2f(u[j]) - m) * inv);
    *(bf16x8*)(&lrow[f * 8]) = o;
  }
}

extern "C" void kernel_launch(void* const* d_in, const int* in_sizes, int n_in,
                              void* d_out, int out_size, void* d_ws, size_t ws_size,
                              hipStream_t stream)
{
  (void)in_sizes; (void)n_in; (void)out_size; (void)ws_size;
  const float* vision = (const float*)d_in[0];   // [2304][1024]
  const float* W1w    = (const float*)d_in[1];   // [4096][1024]
  const float* W1b    = (const float*)d_in[2];   // [4096]
  const float* W2w    = (const float*)d_in[3];   // [32000][4096]
  const float* Emb    = (const float*)d_in[4];   // [32000][4096]
  float* out = (float*)d_out;                    // [2304][4096]

  char* ws = (char*)d_ws;
  bf16_t* xn     = (bf16_t*)ws;                             // 18,874,368 B
  bf16_t* logits = (bf16_t*)(ws + 18874368);                // 147,456,000 B
  float*  xbuf   = (float*)(ws + 18874368 + 147456000);     // 37,748,736 B

  const int Mt = M_TOK / BM;  // 24

  // 1) x = vision @ W1^T + b   (M=2304, N=4096, K=1024) — grid 768 = 3/CU exact
  gemm_k<1, 0, 0><<<dim3(Mt * (DLAT / BN)), dim3(256), 0, stream>>>(
      vision, W1w, xbuf, W1b, DV, DV, DV, DLAT, Mt);

  // 2) xn = LayerNorm(x) -> bf16
  ln_k<<<dim3(M_TOK), dim3(256), 0, stream>>>(xbuf, xn);

  // 3) logits = xn @ W2^T -> bf16   (M=2304, N=32000, K=4096) — grid 6000
  gemm_k<0, 0, 1><<<dim3(Mt * (VOCAB / BN)), dim3(256), 0, stream>>>(
      xn, W2w, logits, nullptr, DLAT, DLAT, DLAT, VOCAB, Mt);

  // 4) P = softmax(logits) in place
  softmax_k<<<dim3(M_TOK), dim3(256), 0, stream>>>(logits);

  // 5) out = P @ Emb   (M=2304, N=4096, K=32000, NN) — grid 768 = 3/CU exact
  gemm_k<0, 1, 2><<<dim3(Mt * (DLAT / BN)), dim3(256), 0, stream>>>(
      logits, Emb, out, nullptr, VOCAB, VOCAB, DLAT, DLAT, Mt);
}